// Round 6
// baseline (142.105 us; speedup 1.0000x reference)
//
#include <hip/hip_runtime.h>
#include <hip/hip_bf16.h>
#include <math.h>

// Problem constants (b=2, n=2048, dim=512, h=8, dh=64, f=256, chunk=128)
#define NB    2
#define NSEQ  2048
#define DIMM  512
#define NH    8
#define DHd   64
#define FF    256
#define CHK   128
#define NCHK  16
#define NBH   16   // NB*NH

typedef unsigned short ushort_t;
typedef __attribute__((ext_vector_type(8))) __bf16 bf16x8;
typedef __attribute__((ext_vector_type(4))) float floatx4;

__device__ __forceinline__ unsigned short f2bf(float x) {
    union { __hip_bfloat16 h; unsigned short u; } v;
    v.h = __float2bfloat16(x);
    return v.u;
}
__device__ __forceinline__ float bf2f(unsigned short u) {
    union { unsigned short u2[2]; float f; } v;
    v.u2[0] = 0; v.u2[1] = u;
    return v.f;
}
__device__ __forceinline__ unsigned enc_f(float x) {
    unsigned u = __float_as_uint(x);
    return (u & 0x80000000u) ? ~u : (u | 0x80000000u);
}
__device__ __forceinline__ float dec_f(unsigned e) {
    unsigned u = (e & 0x80000000u) ? (e & 0x7fffffffu) : ~e;
    return __uint_as_float(u);
}

__device__ __forceinline__ void gload16(const void* g, void* l) {
    __builtin_amdgcn_global_load_lds(
        (const __attribute__((address_space(1))) void*)g,
        (__attribute__((address_space(3))) void*)l, 16, 0, 0);
}

// frag read from a 64-k-step tile (8 granules/row, xor-swizzled)
__device__ __forceinline__ bf16x8 frag8(const ushort_t* lds, int row, int kb) {
    return *((const bf16x8*)lds + row * 8 + (kb ^ (row & 7)));
}
// frag read from a 128-k tile (16 granules/row)
__device__ __forceinline__ bf16x8 fragS(const ushort_t* lds, int row, int kb) {
    return *((const bf16x8*)lds + row * 16 + (kb ^ (row & 15)));
}

// stage a 128-row x 64-k tile (1024 granules) into LDS, frag8 swizzle
__device__ __forceinline__ void stage8(const ushort_t* __restrict__ G, ushort_t* dst,
                                       int ld, int tid) {
#pragma unroll
    for (int t = 0; t < 4; t++) {
        const int g = t * 256 + tid, r = g >> 3, kb = (g & 7) ^ (r & 7);
        gload16(G + (size_t)r * ld + kb * 8, dst + (size_t)g * 8);
    }
}
// stage a 64-row x 64-k tile (512 granules), frag8 swizzle
__device__ __forceinline__ void stage4h(const ushort_t* __restrict__ G, ushort_t* dst,
                                        int ld, int tid) {
#pragma unroll
    for (int t = 0; t < 2; t++) {
        const int g = t * 256 + tid, r = g >> 3, kb = (g & 7) ^ (r & 7);
        gload16(G + (size_t)r * ld + kb * 8, dst + (size_t)g * 8);
    }
}
// stage a 64-row x 128-k tile (1024 granules), fragS swizzle (ld = NSEQ)
__device__ __forceinline__ void stageV(const ushort_t* __restrict__ G, ushort_t* dst,
                                       int tid) {
#pragma unroll
    for (int t = 0; t < 4; t++) {
        const int g = t * 256 + tid, r = g >> 4, kb = (g & 15) ^ (r & 15);
        gload16(G + (size_t)r * NSEQ + kb * 8, dst + (size_t)g * 8);
    }
}

// =====================================================================
// prep: init mk_u + conv x->bf16 + conv proj->bf16(*dn) + transpose W's
// =====================================================================
__global__ __launch_bounds__(256)
void prep(const float* __restrict__ x, const float* __restrict__ proj,
          const float* __restrict__ W0, const float* __restrict__ W1,
          const float* __restrict__ W2, const float* __restrict__ W3,
          ushort_t* __restrict__ xb, ushort_t* __restrict__ projb,
          ushort_t* __restrict__ T0, ushort_t* __restrict__ T1,
          ushort_t* __restrict__ T2, ushort_t* __restrict__ T3,
          unsigned* __restrict__ mk_u)
{
    __shared__ float t[32][33];
    const int b = blockIdx.x, tid = threadIdx.x;
    if (b < 2048) {
        const int gid = b * 256 + tid;
        const float4 v = *(const float4*)(x + (size_t)gid * 4);
        union { ushort4 v4; unsigned short s[4]; } pk;
        pk.s[0] = f2bf(v.x); pk.s[1] = f2bf(v.y); pk.s[2] = f2bf(v.z); pk.s[3] = f2bf(v.w);
        ((ushort4*)xb)[gid] = pk.v4;
    } else if (b < 2064) {
        const int gid = (b - 2048) * 256 + tid;
        const float dn = 0.35355339059327379f;   // 64^-0.25 folded into proj
        const float4 v = *(const float4*)(proj + (size_t)gid * 4);
        union { ushort4 v4; unsigned short s[4]; } pk;
        pk.s[0] = f2bf(v.x * dn); pk.s[1] = f2bf(v.y * dn);
        pk.s[2] = f2bf(v.z * dn); pk.s[3] = f2bf(v.w * dn);
        ((ushort4*)projb)[gid] = pk.v4;
    } else if (b < 3088) {
        const int idx = b - 2064;                // 0..1023
        const int z = idx >> 8, rem = idx & 255;
        const int bx = rem & 15, by = rem >> 4;
        const float* W = (z == 0) ? W0 : (z == 1) ? W1 : (z == 2) ? W2 : W3;
        ushort_t* T = (z == 0) ? T0 : (z == 1) ? T1 : (z == 2) ? T2 : T3;
        const int x0 = bx * 32, y0 = by * 32;
        const int tx = tid & 31, ty = tid >> 5;  // 32 x 8
#pragma unroll
        for (int i = 0; i < 4; i++)
            t[ty + i * 8][tx] = W[(size_t)(y0 + ty + i * 8) * DIMM + x0 + tx];
        __syncthreads();
#pragma unroll
        for (int i = 0; i < 4; i++)
            T[(size_t)(x0 + ty + i * 8) * DIMM + y0 + tx] = f2bf(t[tx][ty + i * 8]);
    } else {
        if (tid < NBH) mk_u[tid] = 0u;
    }
}

// =====================================================================
// MFMA main loop: C[128x128] += A[128xK] * B[128xK]^T
// =====================================================================
__device__ __forceinline__ void mfma_mainloop(
    const ushort_t* __restrict__ AG, const ushort_t* __restrict__ BG,
    ushort_t* As, ushort_t* Bs, int ldA, int ldB, int K,
    floatx4 acc[4][4], int tid)
{
    const int lane = tid & 63, wid = tid >> 6;
    const int q = lane >> 4, c = lane & 15;
    const int wm = (wid >> 1) * 64, wn = (wid & 1) * 64;

    for (int k0 = 0; k0 < K; k0 += 64) {
#pragma unroll
        for (int t = 0; t < 4; t++) {
            const int g = t * 256 + tid, r = g >> 3, kb = (g & 7) ^ (r & 7);
            gload16(AG + (size_t)r * ldA + k0 + kb * 8, As + (size_t)g * 8);
        }
#pragma unroll
        for (int t = 0; t < 4; t++) {
            const int g = t * 256 + tid, r = g >> 3, kb = (g & 7) ^ (r & 7);
            gload16(BG + (size_t)r * ldB + k0 + kb * 8, Bs + (size_t)g * 8);
        }
        __syncthreads();
#pragma unroll
        for (int ks = 0; ks < 2; ks++) {
            bf16x8 af[4], bfr[4];
#pragma unroll
            for (int i = 0; i < 4; i++) {
                af[i]  = frag8(As, wm + i * 16 + c, ks * 4 + q);
                bfr[i] = frag8(Bs, wn + i * 16 + c, ks * 4 + q);
            }
#pragma unroll
            for (int i = 0; i < 4; i++)
#pragma unroll
                for (int j = 0; j < 4; j++)
                    acc[i][j] = __builtin_amdgcn_mfma_f32_16x16x32_bf16(
                        af[i], bfr[j], acc[i][j], 0, 0, 0);
        }
        __syncthreads();
    }
}

// =====================================================================
// QKV projection: 128x128 tiles, grid 384, z = bid%3 interleaved.
// z=0 -> qb, z=1 -> kb, z=2 -> vTb. (key-feature max moved to kmax)
// =====================================================================
__global__ __launch_bounds__(256)
void gemm_qkv(const ushort_t* __restrict__ xb,
              const ushort_t* __restrict__ Wtq, const ushort_t* __restrict__ Wtk,
              const ushort_t* __restrict__ Wtv,
              ushort_t* __restrict__ qb, ushort_t* __restrict__ kb,
              ushort_t* __restrict__ vTb)
{
    __shared__ alignas(16) ushort_t SM[17408];   // staging As/Bs (16384); tile[128][136]
    ushort_t* As = SM;
    ushort_t* Bs = SM + 8192;
    const int tid = threadIdx.x;
    const int bid = blockIdx.x;
    const int z = bid % 3, tt = bid / 3;
    const int n0 = (tt & 3) * 128, m0 = (tt >> 2) * 128;
    const ushort_t* Bt = (z == 0) ? Wtq : ((z == 1) ? Wtk : Wtv);

    floatx4 zero = {0.f, 0.f, 0.f, 0.f};
    floatx4 acc[4][4];
#pragma unroll
    for (int i = 0; i < 4; i++)
#pragma unroll
        for (int j = 0; j < 4; j++) acc[i][j] = zero;

    mfma_mainloop(xb + (size_t)m0 * DIMM, Bt + (size_t)n0 * DIMM, As, Bs,
                  DIMM, DIMM, DIMM, acc, tid);

    const int lane = tid & 63, wid = tid >> 6;
    const int q = lane >> 4, cl = lane & 15;
    const int wm = (wid >> 1) * 64, wn = (wid & 1) * 64;

    // C tile -> LDS (stride 136: 16B-aligned rows)
#pragma unroll
    for (int i = 0; i < 4; i++)
#pragma unroll
        for (int j = 0; j < 4; j++) {
            const int col = wn + j * 16 + cl;
#pragma unroll
            for (int r = 0; r < 4; r++) {
                const int row = wm + i * 16 + q * 4 + r;
                SM[row * 136 + col] = f2bf(acc[i][j][r]);
            }
        }
    __syncthreads();

    if (z < 2) {
        ushort_t* ob = (z == 0) ? qb : kb;
#pragma unroll
        for (int p = 0; p < 16; p++) {
            const int idx = p * 256 + tid;
            const int row = idx >> 5, c4 = idx & 31;
            ushort4 o = *(const ushort4*)&SM[row * 136 + c4 * 4];
            *(ushort4*)(ob + (size_t)(m0 + row) * DIMM + n0 + c4 * 4) = o;
        }
    } else {
        const int bb = m0 >> 11, nbase = m0 & 2047;
#pragma unroll
        for (int p = 0; p < 16; p++) {
            const int idx = p * 256 + tid;
            const int cl2 = idx >> 5, n4 = idx & 31;
            const int C = n0 + cl2;
            const int h = C >> 6, e = C & 63;
            union { ushort4 v4; unsigned short s[4]; } pk;
#pragma unroll
            for (int k = 0; k < 4; k++) pk.s[k] = SM[(n4 * 4 + k) * 136 + cl2];
            *(ushort4*)(vTb + (((size_t)(bb * NH + h) * 64 + e)) * NSEQ + nbase + n4 * 4) = pk.v4;
        }
    }
}

// =====================================================================
// kmax: per-(b,h) max over key features (kb @ proj), grid (32,8,2).
// Bit-identical operands/MFMA to the old fused pass -> identical max.
// =====================================================================
__global__ __launch_bounds__(256)
void kmax(const ushort_t* __restrict__ kb_, const ushort_t* __restrict__ projb,
          unsigned* __restrict__ mk_u)
{
    __shared__ alignas(16) ushort_t As[8192];
    __shared__ alignas(16) ushort_t Bs[8192];
    __shared__ float wred[4];
    const int tid = threadIdx.x, lane = tid & 63, wid = tid >> 6;
    const int q = lane >> 4, cl = lane & 15;
    const int m0 = blockIdx.x * 128, h = blockIdx.y, fh = blockIdx.z;
    const int bb = m0 >> 11;
    const int bh = bb * NH + h;
    const ushort_t* Aq = kb_ + (size_t)m0 * DIMM + h * 64;

    stage8(Aq, As, DIMM, tid);                    // kb chunk 128 x 64
    stage8(projb + (size_t)fh * 128 * 64, Bs, 64, tid);  // proj f-half 128 x 64
    __syncthreads();

    floatx4 zero = {0.f, 0.f, 0.f, 0.f};
    floatx4 acc[4][4];
#pragma unroll
    for (int i = 0; i < 4; i++)
#pragma unroll
        for (int j = 0; j < 4; j++) acc[i][j] = zero;
    const int wm = (wid >> 1) * 64, wn = (wid & 1) * 64;
#pragma unroll
    for (int ks = 0; ks < 2; ks++) {
        bf16x8 af[4], bfr[4];
#pragma unroll
        for (int i = 0; i < 4; i++) af[i] = frag8(As, wm + i * 16 + cl, ks * 4 + q);
#pragma unroll
        for (int j = 0; j < 4; j++) bfr[j] = frag8(Bs, wn + j * 16 + cl, ks * 4 + q);
#pragma unroll
        for (int i = 0; i < 4; i++)
#pragma unroll
            for (int j = 0; j < 4; j++)
                acc[i][j] = __builtin_amdgcn_mfma_f32_16x16x32_bf16(
                    af[i], bfr[j], acc[i][j], 0, 0, 0);
    }

    float mx = -3.0e38f;
#pragma unroll
    for (int i = 0; i < 4; i++)
#pragma unroll
        for (int j = 0; j < 4; j++)
#pragma unroll
            for (int r = 0; r < 4; r++) mx = fmaxf(mx, acc[i][j][r]);
    mx = fmaxf(mx, __shfl_xor(mx, 1));  mx = fmaxf(mx, __shfl_xor(mx, 2));
    mx = fmaxf(mx, __shfl_xor(mx, 4));  mx = fmaxf(mx, __shfl_xor(mx, 8));
    mx = fmaxf(mx, __shfl_xor(mx, 16)); mx = fmaxf(mx, __shfl_xor(mx, 32));
    if (lane == 0) wred[wid] = mx;
    __syncthreads();
    if (tid == 0) {
        const float m = fmaxf(fmaxf(wred[0], wred[1]), fmaxf(wred[2], wred[3]));
        atomicMax(&mk_u[bh], enc_f(m));
    }
}

// ---------- output projection: 64x128 tiles, grid 256, double-buffered ----------
__device__ __forceinline__ void mm24(const ushort_t* A, const ushort_t* B,
                                     floatx4 acc[2][4], int wm, int wn, int c, int q)
{
#pragma unroll
    for (int ks = 0; ks < 2; ks++) {
        bf16x8 af[2], bfr[4];
#pragma unroll
        for (int i = 0; i < 2; i++) af[i] = frag8(A, wm + i * 16 + c, ks * 4 + q);
#pragma unroll
        for (int j = 0; j < 4; j++) bfr[j] = frag8(B, wn + j * 16 + c, ks * 4 + q);
#pragma unroll
        for (int i = 0; i < 2; i++)
#pragma unroll
            for (int j = 0; j < 4; j++)
                acc[i][j] = __builtin_amdgcn_mfma_f32_16x16x32_bf16(
                    af[i], bfr[j], acc[i][j], 0, 0, 0);
    }
}

__global__ __launch_bounds__(256)
void gemm_out(const ushort_t* __restrict__ attnb, const ushort_t* __restrict__ Wto,
              float* __restrict__ out, const float* __restrict__ bias)
{
    __shared__ alignas(16) ushort_t A0[4096];
    __shared__ alignas(16) ushort_t A1[4096];
    __shared__ alignas(16) ushort_t B0[8192];
    __shared__ alignas(16) ushort_t B1[8192];
    const int tid = threadIdx.x;
    const int n0 = blockIdx.x * 128, m0 = blockIdx.y * 64;
    const ushort_t* AG = attnb + (size_t)m0 * DIMM;
    const ushort_t* BG = Wto + (size_t)n0 * DIMM;

    floatx4 zero = {0.f, 0.f, 0.f, 0.f};
    floatx4 acc[2][4];
#pragma unroll
    for (int i = 0; i < 2; i++)
#pragma unroll
        for (int j = 0; j < 4; j++) acc[i][j] = zero;

    const int lane = tid & 63, wid = tid >> 6;
    const int q = lane >> 4, c = lane & 15;
    const int wm = (wid >> 1) * 32, wn = (wid & 1) * 64;

    stage4h(AG, A0, DIMM, tid);
    stage8(BG, B0, DIMM, tid);
    __syncthreads();
    for (int tt = 0; tt < 4; tt++) {
        const int k0 = tt * 128;
        stage4h(AG + k0 + 64, A1, DIMM, tid);
        stage8(BG + k0 + 64, B1, DIMM, tid);
        mm24(A0, B0, acc, wm, wn, c, q);
        __syncthreads();                         // A1/B1 resident; A0/B0 reads done
        if (tt < 3) {
            stage4h(AG + k0 + 128, A0, DIMM, tid);
            stage8(BG + k0 + 128, B0, DIMM, tid);
        }
        mm24(A1, B1, acc, wm, wn, c, q);
        __syncthreads();                         // A0/B0 resident; A1/B1 reads done
    }

#pragma unroll
    for (int i = 0; i < 2; i++)
#pragma unroll
        for (int j = 0; j < 4; j++) {
            const int col = n0 + wn + j * 16 + c;
            const float bv = bias[col];
#pragma unroll
            for (int r = 0; r < 4; r++) {
                const int row = m0 + wm + i * 16 + q * 4 + r;
                out[(size_t)row * DIMM + col] = acc[i][j][r] + bv;
            }
        }
}

// =====================================================================
// featk, f-half blocks: grid (32, 8, 2) = 512 blocks, 2 blocks/CU.
// Each block: kf chunk [128 rows][128 f-half] + Ksum half + CTXT half.
// =====================================================================
__global__ __launch_bounds__(256)
void featk(const ushort_t* __restrict__ kb_, const ushort_t* __restrict__ projb,
           const unsigned* __restrict__ mk_u, const ushort_t* __restrict__ vTb,
           ushort_t* __restrict__ kfb, float* __restrict__ CTXT,
           float* __restrict__ Ksum)
{
    __shared__ alignas(16) ushort_t SM[17408];  // As(8192)+Bs(8192) -> kf-tile[128][136] -> T[64][136]
    __shared__ alignas(16) ushort_t Vs[8192];   // V tile 64 x 128 (fragS), dedicated
    __shared__ float dtmp[256];
    __shared__ float diag_l[128];
    __shared__ float colp[2][128];
    ushort_t* As = SM;
    ushort_t* Bs = SM + 8192;
    const int tid = threadIdx.x, lane = tid & 63, wid = tid >> 6;
    const int q = lane >> 4, cl = lane & 15;
    const int m0 = blockIdx.x * 128, h = blockIdx.y, fh = blockIdx.z;
    const int bb = m0 >> 11, nloc = m0 & 2047;
    const int bh = bb * NH + h;
    const int cidx = nloc >> 7;
    const ushort_t* Aq = kb_ + (size_t)m0 * DIMM + h * 64;
    const ushort_t* Vg = vTb + ((size_t)bh * 64) * NSEQ + nloc;
    const ushort_t* Pj = projb + (size_t)fh * 128 * 64;

    // diag[row] = sum(k^2)/16
    {
        const int row = tid >> 1, half = tid & 1;
        float s = 0.f;
        const ushort_t* p = Aq + (size_t)row * DIMM + half * 32;
#pragma unroll
        for (int d = 0; d < 32; d += 4) {
            ushort4 w = *(const ushort4*)(p + d);
            float a = bf2f(w.x), b2 = bf2f(w.y), c2 = bf2f(w.z), d2 = bf2f(w.w);
            s += a * a + b2 * b2 + c2 * c2 + d2 * d2;
        }
        dtmp[tid] = s;
    }
    stage8(Aq, As, DIMM, tid);      // kb chunk 128 x 64
    stage8(Pj, Bs, 64, tid);        // proj f-half 128 x 64
    stageV(Vg, Vs, tid);            // V tile 64 x 128
    __syncthreads();                                    // S0
    if (tid < 128) diag_l[tid] = (dtmp[2 * tid] + dtmp[2 * tid + 1]) * 0.0625f;

    floatx4 zero = {0.f, 0.f, 0.f, 0.f};
    floatx4 acc[4][4];
#pragma unroll
    for (int i = 0; i < 4; i++)
#pragma unroll
        for (int j = 0; j < 4; j++) acc[i][j] = zero;
    const int wm = (wid >> 1) * 64, wn = (wid & 1) * 64;
#pragma unroll
    for (int ks = 0; ks < 2; ks++) {
        bf16x8 af[4], bfr[4];
#pragma unroll
        for (int i = 0; i < 4; i++) af[i] = frag8(As, wm + i * 16 + cl, ks * 4 + q);
#pragma unroll
        for (int j = 0; j < 4; j++) bfr[j] = frag8(Bs, wn + j * 16 + cl, ks * 4 + q);
#pragma unroll
        for (int i = 0; i < 4; i++)
#pragma unroll
            for (int j = 0; j < 4; j++)
                acc[i][j] = __builtin_amdgcn_mfma_f32_16x16x32_bf16(
                    af[i], bfr[j], acc[i][j], 0, 0, 0);
    }
    __syncthreads();                                    // S1: frag reads done; diag_l visible

    const float mk = dec_f(mk_u[bh]);
#pragma unroll
    for (int i = 0; i < 4; i++)
#pragma unroll
        for (int r = 0; r < 4; r++) {
            const int row = wm + i * 16 + q * 4 + r;
            const float cc = diag_l[row] + mk;
#pragma unroll
            for (int j = 0; j < 4; j++)
                acc[i][j][r] = 0.0625f * (__expf(acc[i][j][r] - cc) + 1.0e-4f);
        }

    // column sums (over 128 rows): colp[row-group][col]
#pragma unroll
    for (int j = 0; j < 4; j++) {
        float s = 0.f;
#pragma unroll
        for (int i = 0; i < 4; i++)
            s += acc[i][j][0] + acc[i][j][1] + acc[i][j][2] + acc[i][j][3];
        s += __shfl_xor(s, 16);
        s += __shfl_xor(s, 32);
        if (q == 0) colp[wid >> 1][wn + j * 16 + cl] = s;
    }

    // kf tile -> SM (stride 136, 16B-aligned rows)
#pragma unroll
    for (int i = 0; i < 4; i++)
#pragma unroll
        for (int j = 0; j < 4; j++) {
            const int col = wn + j * 16 + cl;
#pragma unroll
            for (int r = 0; r < 4; r++) {
                const int row = wm + i * 16 + q * 4 + r;
                SM[row * 136 + col] = f2bf(acc[i][j][r]);
            }
        }
    __syncthreads();                                    // S2: tile + colp visible

    if (tid < 128)
        Ksum[((size_t)bh * NCHK + cidx) * FF + fh * 128 + tid] = colp[0][tid] + colp[1][tid];

    const size_t frow = (size_t)bh * NSEQ + nloc;
#pragma unroll
    for (int p = 0; p < 16; p++) {
        const int idx = p * 256 + tid;
        const int row = idx >> 5, c4 = idx & 31;
        ushort4 o = *(const ushort4*)&SM[row * 136 + c4 * 4];
        *(ushort4*)(kfb + (frow + row) * FF + fh * 128 + c4 * 4) = o;
    }
    __syncthreads();                                    // S3: SM reads done (T reuse)

    // fused ctx: CTXT[bh][cidx][e][fh*128 + f] = sum_n vT[e][n] * kf[n][f]
    ushort_t* T = SM;
    const size_t cbase = ((size_t)bh * NCHK + cidx) * 64;
#pragma unroll
    for (int fq = 0; fq < 2; fq++) {
        if ((wid & 1) == fq) {
#pragma unroll
            for (int jj = 0; jj < 4; jj++) {
#pragma unroll
                for (int i = 0; i < 4; i++)
#pragma unroll
                    for (int r = 0; r < 4; r++) {
                        const int n = wm + i * 16 + q * 4 + r;
                        T[(jj * 16 + cl) * 136 + n] = f2bf(acc[i][jj][r]);
                    }
            }
        }
        __syncthreads();                                // T ready
        floatx4 accc[4];
#pragma unroll
        for (int jj = 0; jj < 4; jj++) accc[jj] = zero;
#pragma unroll
        for (int kt = 0; kt < 4; kt++) {
            const bf16x8 av = fragS(Vs, wid * 16 + cl, kt * 4 + q);
#pragma unroll
            for (int jj = 0; jj < 4; jj++) {
                const bf16x8 bv = *(const bf16x8*)(T + (jj * 16 + cl) * 136 + (kt * 4 + q) * 8);
                accc[jj] = __builtin_amdgcn_mfma_f32_16x16x32_bf16(av, bv, accc[jj], 0, 0, 0);
            }
        }
#pragma unroll
        for (int jj = 0; jj < 4; jj++) {
            const int f = fh * 128 + fq * 64 + jj * 16 + cl;
#pragma unroll
            for (int r = 0; r < 4; r++) {
                const int e = wid * 16 + q * 4 + r;
                CTXT[(cbase + e) * FF + f] = accc[jj][r];
            }
        }
        __syncthreads();
    }
}

// ---------- merged exclusive prefixes: blocks [0,1024) S-path, [1024,1040) Z-path ----------
__global__ void prefix_zs(float* __restrict__ Ksum, float* __restrict__ Zout,
                          const float* __restrict__ CTXT, ushort_t* __restrict__ ctxp,
                          float* __restrict__ Sout)
{
    const int b = blockIdx.x;
    if (b < 1024) {
        const int idx = b * 256 + threadIdx.x;
        const int bh = idx >> 14, ef = idx & 16383;
        const int e = ef >> 8, f = ef & 255;
        float run = 0.f;
#pragma unroll
        for (int c = 0; c < NCHK; c++) {
            const size_t o = (((size_t)bh * NCHK + c) * 64 + e) * FF + f;
            const float t = CTXT[o];
            ctxp[o] = f2bf(run);
            run += t;
        }
        Sout[((size_t)bh * FF + f) * 64 + e] = run;   // S[b,h,f,e]
    } else {
        const int idx = (b - 1024) * 256 + threadIdx.x;
        const int bh = idx >> 8, f = idx & 255;
        float run = 0.f;
#pragma unroll
        for (int c = 0; c < NCHK; c++) {
            const size_t o = ((size_t)(bh * NCHK + c)) * FF + f;
            const float t = Ksum[o];
            Ksum[o] = run;
            run += t;
        }
        Zout[(size_t)bh * FF + f] = run;
    }
}

// ---- stage-1 k-step: acc1[j] += qf_slice x Kf_tile (A rows = wave's 16 q-rows)
template<int NJ>
__device__ __forceinline__ void st1N(const ushort_t* QFs, const ushort_t* Bk,
                                     floatx4* acc1, int wv, int cl, int q)
{
#pragma unroll
    for (int ks = 0; ks < 2; ks++) {
        const bf16x8 af = frag8(QFs, wv * 16 + cl, ks * 4 + q);
        bf16x8 bfr[NJ];
#pragma unroll
        for (int j = 0; j < NJ; j++) bfr[j] = frag8(Bk, j * 16 + cl, ks * 4 + q);
#pragma unroll
        for (int j = 0; j < NJ; j++)
            acc1[j] = __builtin_amdgcn_mfma_f32_16x16x32_bf16(af, bfr[j], acc1[j], 0, 0, 0);
    }
}

// ---- stage-4 k-tile: acc2[i] += Cp_tile x qf_slice
__device__ __forceinline__ void pv4(const ushort_t* CpB, const ushort_t* QFs,
                                    floatx4 acc2[4], int wv, int cl, int q)
{
#pragma unroll
    for (int ks = 0; ks < 2; ks++) {
        const bf16x8 bfr = frag8(QFs, wv * 16 + cl, ks * 4 + q);
#pragma unroll
        for (int i = 0; i < 4; i++) {
            const bf16x8 af = frag8(CpB, i * 16 + cl, ks * 4 + q);
            acc2[i] = __builtin_amdgcn_mfma_f32_16x16x32_bf16(af, bfr, acc2[i], 0, 0, 0);
        }
    }
}

// =====================================================================
// chunk output, half-chunk blocks: 512 blocks (bh x chunk x half),
// 64 q-rows each, 2 blocks/CU. hq=0 blocks skip the fully-masked upper
// 64 KV columns: half Kf staging, half st1 MFMAs, half V/stage-3 work.
// =====================================================================
__global__ __launch_bounds__(256)
void chunk_out_half(const ushort_t* __restrict__ qb_, const ushort_t* __restrict__ projb,
                    const ushort_t* __restrict__ kfb, const ushort_t* __restrict__ vTb,
                    const float* __restrict__ Zex, const ushort_t* __restrict__ ctxp,
                    ushort_t* __restrict__ attnb)
{
    __shared__ alignas(16) ushort_t QF[16384];   // 32KB: qf [64 rows][256 f], 4 frag8 slices
    __shared__ alignas(16) ushort_t BufA[8192];  // 16KB: proj h0 / Kf odd / Vt / Cp1-2
    __shared__ alignas(16) ushort_t Ssl[8192];   // 16KB: proj h1 / Kf even / S / out-tile
    __shared__ alignas(16) ushort_t BufB[4096];  // 8KB:  q tile / Cp0 / Cp3
    __shared__ float zeps[256];
    __shared__ float dtmp[256];
    __shared__ float diag_l[64];
    __shared__ float rows_part[64];
    __shared__ float denp[256];
    __shared__ float den_l[64];

    const int tid = threadIdx.x, lane = tid & 63, wv = tid >> 6;
    const int q = lane >> 4, cl = lane & 15;
    const int bh = blockIdx.x >> 5, r5 = blockIdx.x & 31;
    const int c = r5 >> 1, hq = r5 & 1;
    const int bb = bh >> 3, h = bh & 7;
    const int n0 = c * CHK, q0 = n0 + hq * 64;
    const ushort_t* Kf = kfb + ((size_t)bh * NSEQ + n0) * FF;
    const ushort_t* Aq = qb_ + ((size_t)(bb * NSEQ + q0)) * DIMM + h * 64;
    const ushort_t* Vt = vTb + ((size_t)bh * 64) * NSEQ + n0;
    const ushort_t* Cp = ctxp + ((size_t)bh * NCHK + c) * 64 * FF;

    zeps[tid] = Zex[((size_t)bh * NCHK + c) * FF + tid] + 1.0e-6f;

    // P0: stage q + both proj halves; diag under the same drain
    stage4h(Aq, BufB, DIMM, tid);
    stage8(projb, BufA, 64, tid);
    stage8(projb + 128 * 64, Ssl, 64, tid);
    {
        const int row = tid >> 2, qd = tid & 3;
        float s = 0.f;
        const ushort_t* p = Aq + (size_t)row * DIMM + qd * 16;
#pragma unroll
        for (int d = 0; d < 16; d += 4) {
            ushort4 w = *(const ushort4*)(p + d);
            float a = bf2f(w.x), b2 = bf2f(w.y), c2 = bf2f(w.z), d2 = bf2f(w.w);
            s += a * a + b2 * b2 + c2 * c2 + d2 * d2;
        }
        dtmp[tid] = s;
    }
    __syncthreads();                                   // S0
    if (tid < 64)
        diag_l[tid] = (dtmp[4 * tid] + dtmp[4 * tid + 1] +
                       dtmp[4 * tid + 2] + dtmp[4 * tid + 3]) * 0.0625f;

    floatx4 zero = {0.f, 0.f, 0.f, 0.f};
    floatx4 accqA[8], accqB[8];
#pragma unroll
    for (int j = 0; j < 8; j++) { accqA[j] = zero; accqB[j] = zero; }
    // qf = q @ proj^T, f-half0 (BufA) and f-half1 (Ssl)
#pragma unroll
    for (int ks = 0; ks < 2; ks++) {
        const bf16x8 af = frag8(BufB, wv * 16 + cl, ks * 4 + q);
#pragma unroll
        for (int j = 0; j < 8; j++) {
            const bf16x8 b0 = frag8(BufA, j * 16 + cl, ks * 4 + q);
            accqA[j] = __builtin_amdgcn_mfma_f32_16x16x32_bf16(af, b0, accqA[j], 0, 0, 0);
        }
#pragma unroll
        for (int j = 0; j < 8; j++) {
            const bf16x8 b1 = frag8(Ssl, j * 16 + cl, ks * 4 + q);
            accqB[j] = __builtin_amdgcn_mfma_f32_16x16x32_bf16(af, b1, accqB[j], 0, 0, 0);
        }
    }
    // per-row max (in-register, shfl over cl lanes)
    float rmax[4];
#pragma unroll
    for (int r = 0; r < 4; r++) {
        float m = -3.0e38f;
#pragma unroll
        for (int j = 0; j < 8; j++) m = fmaxf(m, fmaxf(accqA[j][r], accqB[j][r]));
        m = fmaxf(m, __shfl_xor(m, 1)); m = fmaxf(m, __shfl_xor(m, 2));
        m = fmaxf(m, __shfl_xor(m, 4)); m = fmaxf(m, __shfl_xor(m, 8));
        rmax[r] = m;
    }
    __syncthreads();                                   // S1: all proj/q frag reads done
    // exp + QF write (frag8 layout per 64-f slice)
#pragma unroll
    for (int r = 0; r < 4; r++) {
        const int rowL = wv * 16 + q * 4 + r;
        const float cc = diag_l[rowL] + rmax[r];
#pragma unroll
        for (int j = 0; j < 8; j++) {
            {
                const int col = j * 16 + cl;
                const float v = 0.0625f * (__expf(accqA[j][r] - cc) + 1.0e-4f);
                const int s = col >> 6, fp = col & 63;
                QF[s * 4096 + (rowL * 8 + ((fp >> 3) ^ (rowL & 7))) * 8 + (fp & 7)] = f2bf(v);
            }
            {
                const int col = 128 + j * 16 + cl;
                const float v = 0.0625f * (__expf(accqB[j][r] - cc) + 1.0e-4f);
                const int s = col >> 6, fp = col & 63;
                QF[s * 4096 + (rowL * 8 + ((fp >> 3) ^ (rowL & 7))) * 8 + (fp & 7)] = f2bf(v);
            }
        }
    }
    // issue Kf tile0 -> Ssl (after all QF ds_writes; drained at S2)
    if (hq) stage8(Kf, Ssl, FF, tid); else stage4h(Kf, Ssl, FF, tid);
    __syncthreads();                                   // S2: QF + Kf t0 resident

    // ---- stage 1: S = Q @ Kf^T (K=256); issue next tile, compute current ----
    floatx4 acc1[8];
#pragma unroll
    for (int j = 0; j < 8; j++) acc1[j] = zero;
    if (hq) {
        stage8(Kf + 64, BufA, FF, tid);
        st1N<8>(QF, Ssl, acc1, wv, cl, q);             // t0
        __syncthreads();                               // S3
        stage8(Kf + 128, Ssl, FF, tid);
        st1N<8>(QF + 4096, BufA, acc1, wv, cl, q);     // t1
        __syncthreads();                               // S4
        stage8(Kf + 192, BufA, FF, tid);
        st1N<8>(QF + 8192, Ssl, acc1, wv, cl, q);      // t2
        __syncthreads();                               // S5
        st1N<8>(QF + 12288, BufA, acc1, wv, cl, q);    // t3
    } else {
        stage4h(Kf + 64, BufA, FF, tid);
        st1N<4>(QF, Ssl, acc1, wv, cl, q);             // t0
        __syncthreads();                               // S3
        stage4h(Kf + 128, Ssl, FF, tid);
        st1N<4>(QF + 4096, BufA, acc1, wv, cl, q);     // t1
        __syncthreads();                               // S4
        stage4h(Kf + 192, BufA, FF, tid);
        st1N<4>(QF + 8192, Ssl, acc1, wv, cl, q);      // t2
        __syncthreads();                               // S5
        st1N<4>(QF + 12288, BufA, acc1, wv, cl, q);    // t3
    }

    // causal mask + rowsum + S -> Ssl (fragS layout, 64 rows x 16 granules)
    if (hq) {
#pragma unroll
        for (int r = 0; r < 4; r++) {
            const int rowL = wv * 16 + q * 4 + r;
            const int rowG = 64 + rowL;
            float part = 0.f;
#pragma unroll
            for (int j = 0; j < 8; j++) {
                const int col = j * 16 + cl;
                const float v = (col <= rowG) ? acc1[j][r] : 0.f;
                part += v;
                Ssl[(rowL * 16 + ((col >> 3) ^ (rowL & 15))) * 8 + (col & 7)] = f2bf(v);
            }
            part += __shfl_xor(part, 1); part += __shfl_xor(part, 2);
            part += __shfl_xor(part, 4); part += __shfl_xor(part, 8);
            if (cl == 0) rows_part[rowL] = part;
        }
    } else {
#pragma unroll
        for (int r = 0; r < 4; r++) {
            const int rowL = wv * 16 + q * 4 + r;
            float part = 0.f;
#pragma unroll
            for (int j = 0; j < 4; j++) {
                const int col = j * 16 + cl;
                const float v = (col <= rowL) ? acc1[j][r] : 0.f;
                part += v;
                Ssl[(rowL * 16 + ((col >> 3) ^ (rowL & 15))) * 8 + (col & 7)] = f2bf(v);
            }
            part += __shfl_xor(part, 1); part += __shfl_xor(part, 2);
            part += __shfl_xor(part, 4); part += __shfl_xor(part, 8);
            if (cl == 0) rows_part[rowL] = part;
        }
    }
    __syncthreads();                                   // S6: S visible; t3 reads done

    // issue Vt + Cp0; den partial (register-only) under the same drain
    if (hq) stageV(Vt, BufA, tid); else stage4h(Vt, BufA, NSEQ, tid);  // half-V in frag8 layout
    stage4h(Cp, BufB, FF, tid);
    float dacc = 0.f;
    {
        const int drow = tid >> 2, dq = tid & 3;
        const ushort_t* QQ = QF + dq * 4096;
#pragma unroll
        for (int gi = 0; gi < 8; gi++) {
            const ushort_t* gp = QQ + ((size_t)drow * 8 + (gi ^ (drow & 7))) * 8;
            const int kbase = dq * 64 + gi * 8;
#pragma unroll
            for (int e2 = 0; e2 < 8; e2++)
                dacc = fmaf(bf2f(gp[e2]), zeps[kbase + e2], dacc);
        }
    }
    __syncthreads();                                   // S7: Vt + Cp0 resident

    // ---- stage 3: acc2[e] += vT x S (K = 128 or 64 seq) ----
    floatx4 acc2[4];
#pragma unroll
    for (int i = 0; i < 4; i++) acc2[i] = zero;
    if (hq) {
#pragma unroll
        for (int kk = 0; kk < 4; kk++) {
            const bf16x8 bfr = fragS(Ssl, wv * 16 + cl, kk * 4 + q);
#pragma unroll
            for (int i = 0; i < 4; i++) {
                const bf16x8 af = fragS(BufA, i * 16 + cl, kk * 4 + q);
                acc2[i] = __builtin_amdgcn_mfma_f32_16x16x32_bf16(af, bfr, acc2[i], 0, 0, 0);
            }
        }
    } else {
#pragma unroll
        for (int kk = 0; kk < 2; kk++) {
            const bf16x8 bfr = fragS(Ssl, wv * 16 + cl, kk * 4 + q);
#pragma unroll
            for (int i = 0; i < 4; i++) {
                const bf16x8 af = frag8(BufA, i * 16 + cl, kk * 4 + q);
                acc2[i] = __builtin_amdgcn_mfma_f32_16x16x32_bf16(af, bfr, acc2[i], 0, 0, 0);
            }
        }
    }
    denp[tid] = dacc;
    __syncthreads();                                   // S8: Vt/S reads done

    // ---- stage 4: acc2 += ctxp x qf (K = 256 features) ----
    stage4h(Cp + 64, BufA, FF, tid);
    stage4h(Cp + 128, BufA + 4096, FF, tid);
    pv4(BufB, QF, acc2, wv, cl, q);                    // Cp tile 0
    __syncthreads();                                   // S9: Cp1/2 resident
    stage4h(Cp + 192, BufB, FF, tid);
    pv4(BufA, QF + 4096, acc2, wv, cl, q);             // Cp tile 1
    pv4(BufA + 4096, QF + 8192, acc2, wv, cl, q);      // Cp tile 2
    if (tid < 64)
        den_l[tid] = rows_part[tid] + denp[4 * tid] + denp[4 * tid + 1] +
                     denp[4 * tid + 2] + denp[4 * tid + 3];
    __syncthreads();                                   // S10: Cp3 resident; den_l visible
    pv4(BufB, QF + 12288, acc2, wv, cl, q);            // Cp tile 3

    // ---- epilogue: divide, transpose via LDS, coalesced bf16 store ----
    const float dinv = 1.0f / den_l[wv * 16 + cl];
#pragma unroll
    for (int i = 0; i < 4; i++)
#pragma unroll
        for (int r = 0; r < 4; r++) {
            const int e = i * 16 + q * 4 + r;
            Ssl[(wv * 16 + cl) * 68 + e] = f2bf(acc2[i][r] * dinv);
        }
    __syncthreads();                                   // S11
#pragma unroll
    for (int p = 0; p < 4; p++) {
        const int idx = p * 256 + tid;
        const int row = idx >> 4, e4 = idx & 15;
        ushort4 o = *(const ushort4*)&Ssl[row * 68 + e4 * 4];
        *(ushort4*)(attnb + ((size_t)(bb * NSEQ + q0 + row)) * DIMM + h * 64 + e4 * 4) = o;
    }
}

extern "C" void kernel_launch(void* const* d_in, const int* in_sizes, int n_in,
                              void* d_out, int out_size, void* d_ws, size_t ws_size,
                              hipStream_t stream)
{
    (void)in_sizes; (void)n_in; (void)out_size; (void)ws_size;
    const float* x    = (const float*)d_in[0];
    const float* proj = (const float*)d_in[1];
    const float* Wq   = (const float*)d_in[2];
    const float* Wk   = (const float*)d_in[3];
    const float* Wv   = (const float*)d_in[4];
    const float* Wo   = (const float*)d_in[5];
    const float* bo   = (const float*)d_in[6];
    float* out = (float*)d_out;

    // ---- workspace carve (~61 MB) ----
    char* W = (char*)d_ws;
    float*    CTXT = (float*)W;              W += (size_t)16777216;   // [bh][c][e][f] fp32
    ushort_t* kfb  = (ushort_t*)W;           W += (size_t)16777216;   // [bh][n][f] bf16
    ushort_t* ctxp = (ushort_t*)W;           W += (size_t)8388608;    // [bh][c][e][f] bf16
    ushort_t* qb   = (ushort_t*)W;           W += (size_t)4194304;    // [n][dim] bf16 (live into chunk_out)
    ushort_t* kb   = (ushort_t*)W;           W += (size_t)4194304;
    ushort_t* xb   = (ushort_t*)W;           W += (size_t)4194304;    // reused as attnb
    ushort_t* vTb  = (ushort_t*)W;           W += (size_t)4194304;    // [bh][e][n]
    ushort_t* Wtq  = (ushort_t*)W;           W += (size_t)524288;
    ushort_t* Wtk  = (ushort_t*)W;           W += (size_t)524288;
    ushort_t* Wtv  = (ushort_t*)W;           W += (size_t)524288;
    ushort_t* Wto  = (ushort_t*)W;           W += (size_t)524288;
    ushort_t* projb = (ushort_t*)W;          W += (size_t)32768;
    float*    Ksum = (float*)W;              W += (size_t)262144;     // [bh][c][f]
    unsigned* mk_u = (unsigned*)W;           W += (size_t)256;

    ushort_t* attnb = xb;          // xb dead after gemm_qkv

    float* Zout = out + (size_t)4096 * 512;
    float* Sout = Zout + (size_t)NBH * FF;

    hipLaunchKernelGGL(prep, dim3(3089), dim3(256), 0, stream,
                       x, proj, Wq, Wk, Wv, Wo, xb, projb, Wtq, Wtk, Wtv, Wto, mk_u);
    hipLaunchKernelGGL(gemm_qkv, dim3(384), dim3(256), 0, stream,
                       xb, Wtq, Wtk, Wtv, qb, kb, vTb);
    hipLaunchKernelGGL(kmax, dim3(32, 8, 2), dim3(256), 0, stream,
                       kb, projb, mk_u);
    hipLaunchKernelGGL(featk, dim3(32, 8, 2), dim3(256), 0, stream,
                       kb, projb, mk_u, vTb, kfb, CTXT, Ksum);
    hipLaunchKernelGGL(prefix_zs, dim3(1040), dim3(256), 0, stream,
                       Ksum, Zout, CTXT, ctxp, Sout);
    hipLaunchKernelGGL(chunk_out_half, dim3(512), dim3(256), 0, stream,
                       qb, projb, kfb, vTb, Ksum, ctxp, attnb);
    hipLaunchKernelGGL(gemm_out, dim3(4, 64), dim3(256), 0, stream, attnb, Wto, out, bo);
}

// Round 7
// 135.173 us; speedup vs baseline: 1.0513x; 1.0513x over previous
//
#include <hip/hip_runtime.h>
#include <hip/hip_bf16.h>
#include <math.h>

// Problem constants (b=2, n=2048, dim=512, h=8, dh=64, f=256, chunk=128)
#define NB    2
#define NSEQ  2048
#define DIMM  512
#define NH    8
#define DHd   64
#define FF    256
#define CHK   128
#define NCHK  16
#define NBH   16   // NB*NH

typedef unsigned short ushort_t;
typedef __attribute__((ext_vector_type(8))) __bf16 bf16x8;
typedef __attribute__((ext_vector_type(4))) float floatx4;

__device__ __forceinline__ unsigned short f2bf(float x) {
    union { __hip_bfloat16 h; unsigned short u; } v;
    v.h = __float2bfloat16(x);
    return v.u;
}
__device__ __forceinline__ float bf2f(unsigned short u) {
    union { unsigned short u2[2]; float f; } v;
    v.u2[0] = 0; v.u2[1] = u;
    return v.f;
}
__device__ __forceinline__ unsigned enc_f(float x) {
    unsigned u = __float_as_uint(x);
    return (u & 0x80000000u) ? ~u : (u | 0x80000000u);
}
__device__ __forceinline__ float dec_f(unsigned e) {
    unsigned u = (e & 0x80000000u) ? (e & 0x7fffffffu) : ~e;
    return __uint_as_float(u);
}

__device__ __forceinline__ void gload16(const void* g, void* l) {
    __builtin_amdgcn_global_load_lds(
        (const __attribute__((address_space(1))) void*)g,
        (__attribute__((address_space(3))) void*)l, 16, 0, 0);
}

// frag read from a 64-k-step tile (8 granules/row, xor-swizzled)
__device__ __forceinline__ bf16x8 frag8(const ushort_t* lds, int row, int kb) {
    return *((const bf16x8*)lds + row * 8 + (kb ^ (row & 7)));
}
// frag read from a 128-k tile (16 granules/row)
__device__ __forceinline__ bf16x8 fragS(const ushort_t* lds, int row, int kb) {
    return *((const bf16x8*)lds + row * 16 + (kb ^ (row & 15)));
}

// stage a 128-row x 64-k tile (1024 granules) into LDS, frag8 swizzle
__device__ __forceinline__ void stage8(const ushort_t* __restrict__ G, ushort_t* dst,
                                       int ld, int tid) {
#pragma unroll
    for (int t = 0; t < 4; t++) {
        const int g = t * 256 + tid, r = g >> 3, kb = (g & 7) ^ (r & 7);
        gload16(G + (size_t)r * ld + kb * 8, dst + (size_t)g * 8);
    }
}
// stage a 64-row x 64-k tile (512 granules), frag8 swizzle
__device__ __forceinline__ void stage4h(const ushort_t* __restrict__ G, ushort_t* dst,
                                        int ld, int tid) {
#pragma unroll
    for (int t = 0; t < 2; t++) {
        const int g = t * 256 + tid, r = g >> 3, kb = (g & 7) ^ (r & 7);
        gload16(G + (size_t)r * ld + kb * 8, dst + (size_t)g * 8);
    }
}
// stage a 64-row x 128-k tile (1024 granules), fragS swizzle (ld = NSEQ)
__device__ __forceinline__ void stageV(const ushort_t* __restrict__ G, ushort_t* dst,
                                       int tid) {
#pragma unroll
    for (int t = 0; t < 4; t++) {
        const int g = t * 256 + tid, r = g >> 4, kb = (g & 15) ^ (r & 15);
        gload16(G + (size_t)r * NSEQ + kb * 8, dst + (size_t)g * 8);
    }
}

// =====================================================================
// prep: init mk_u + conv x->bf16 + conv proj->bf16(*dn) + transpose W's
// =====================================================================
__global__ __launch_bounds__(256)
void prep(const float* __restrict__ x, const float* __restrict__ proj,
          const float* __restrict__ W0, const float* __restrict__ W1,
          const float* __restrict__ W2, const float* __restrict__ W3,
          ushort_t* __restrict__ xb, ushort_t* __restrict__ projb,
          ushort_t* __restrict__ T0, ushort_t* __restrict__ T1,
          ushort_t* __restrict__ T2, ushort_t* __restrict__ T3,
          unsigned* __restrict__ mk_u)
{
    __shared__ float t[32][33];
    const int b = blockIdx.x, tid = threadIdx.x;
    if (b < 2048) {
        const int gid = b * 256 + tid;
        const float4 v = *(const float4*)(x + (size_t)gid * 4);
        union { ushort4 v4; unsigned short s[4]; } pk;
        pk.s[0] = f2bf(v.x); pk.s[1] = f2bf(v.y); pk.s[2] = f2bf(v.z); pk.s[3] = f2bf(v.w);
        ((ushort4*)xb)[gid] = pk.v4;
    } else if (b < 2064) {
        const int gid = (b - 2048) * 256 + tid;
        const float dn = 0.35355339059327379f;   // 64^-0.25 folded into proj
        const float4 v = *(const float4*)(proj + (size_t)gid * 4);
        union { ushort4 v4; unsigned short s[4]; } pk;
        pk.s[0] = f2bf(v.x * dn); pk.s[1] = f2bf(v.y * dn);
        pk.s[2] = f2bf(v.z * dn); pk.s[3] = f2bf(v.w * dn);
        ((ushort4*)projb)[gid] = pk.v4;
    } else if (b < 3088) {
        const int idx = b - 2064;                // 0..1023
        const int z = idx >> 8, rem = idx & 255;
        const int bx = rem & 15, by = rem >> 4;
        const float* W = (z == 0) ? W0 : (z == 1) ? W1 : (z == 2) ? W2 : W3;
        ushort_t* T = (z == 0) ? T0 : (z == 1) ? T1 : (z == 2) ? T2 : T3;
        const int x0 = bx * 32, y0 = by * 32;
        const int tx = tid & 31, ty = tid >> 5;  // 32 x 8
#pragma unroll
        for (int i = 0; i < 4; i++)
            t[ty + i * 8][tx] = W[(size_t)(y0 + ty + i * 8) * DIMM + x0 + tx];
        __syncthreads();
#pragma unroll
        for (int i = 0; i < 4; i++)
            T[(size_t)(x0 + ty + i * 8) * DIMM + y0 + tx] = f2bf(t[tx][ty + i * 8]);
    } else {
        if (tid < NBH) mk_u[tid] = 0u;
    }
}

// =====================================================================
// MFMA main loop: C[128x128] += A[128xK] * B[128xK]^T
// =====================================================================
__device__ __forceinline__ void mfma_mainloop(
    const ushort_t* __restrict__ AG, const ushort_t* __restrict__ BG,
    ushort_t* As, ushort_t* Bs, int ldA, int ldB, int K,
    floatx4 acc[4][4], int tid)
{
    const int lane = tid & 63, wid = tid >> 6;
    const int q = lane >> 4, c = lane & 15;
    const int wm = (wid >> 1) * 64, wn = (wid & 1) * 64;

    for (int k0 = 0; k0 < K; k0 += 64) {
#pragma unroll
        for (int t = 0; t < 4; t++) {
            const int g = t * 256 + tid, r = g >> 3, kb = (g & 7) ^ (r & 7);
            gload16(AG + (size_t)r * ldA + k0 + kb * 8, As + (size_t)g * 8);
        }
#pragma unroll
        for (int t = 0; t < 4; t++) {
            const int g = t * 256 + tid, r = g >> 3, kb = (g & 7) ^ (r & 7);
            gload16(BG + (size_t)r * ldB + k0 + kb * 8, Bs + (size_t)g * 8);
        }
        __syncthreads();
#pragma unroll
        for (int ks = 0; ks < 2; ks++) {
            bf16x8 af[4], bfr[4];
#pragma unroll
            for (int i = 0; i < 4; i++) {
                af[i]  = frag8(As, wm + i * 16 + c, ks * 4 + q);
                bfr[i] = frag8(Bs, wn + i * 16 + c, ks * 4 + q);
            }
#pragma unroll
            for (int i = 0; i < 4; i++)
#pragma unroll
                for (int j = 0; j < 4; j++)
                    acc[i][j] = __builtin_amdgcn_mfma_f32_16x16x32_bf16(
                        af[i], bfr[j], acc[i][j], 0, 0, 0);
        }
        __syncthreads();
    }
}

// =====================================================================
// QKV projection: 128x128 tiles, grid 384, z = bid%3 interleaved.
// z=0 -> qb, z=1 -> kb (+ fused key-feature max), z=2 -> vTb.
// =====================================================================
__global__ __launch_bounds__(256)
void gemm_qkv(const ushort_t* __restrict__ xb,
              const ushort_t* __restrict__ Wtq, const ushort_t* __restrict__ Wtk,
              const ushort_t* __restrict__ Wtv, const ushort_t* __restrict__ projb,
              ushort_t* __restrict__ qb, ushort_t* __restrict__ kb,
              ushort_t* __restrict__ vTb, unsigned* __restrict__ mk_u)
{
    __shared__ alignas(16) ushort_t SM[25600];   // staging As/Bs; tile[128][136]; PS proj half
    __shared__ float red[256];
    ushort_t* As = SM;
    ushort_t* Bs = SM + 8192;
    ushort_t* PS = SM + 17408;                   // 8192 ushorts: 128f x 64k proj half
    const int tid = threadIdx.x;
    const int bid = blockIdx.x;
    const int z = bid % 3, tt = bid / 3;
    const int n0 = (tt & 3) * 128, m0 = (tt >> 2) * 128;
    const ushort_t* Bt = (z == 0) ? Wtq : ((z == 1) ? Wtk : Wtv);

    floatx4 zero = {0.f, 0.f, 0.f, 0.f};
    floatx4 acc[4][4];
#pragma unroll
    for (int i = 0; i < 4; i++)
#pragma unroll
        for (int j = 0; j < 4; j++) acc[i][j] = zero;

    mfma_mainloop(xb + (size_t)m0 * DIMM, Bt + (size_t)n0 * DIMM, As, Bs,
                  DIMM, DIMM, DIMM, acc, tid);

    const int lane = tid & 63, wid = tid >> 6;
    const int q = lane >> 4, cl = lane & 15;
    const int wm = (wid >> 1) * 64, wn = (wid & 1) * 64;

    // C tile -> LDS (stride 136: 16B-aligned rows)
#pragma unroll
    for (int i = 0; i < 4; i++)
#pragma unroll
        for (int j = 0; j < 4; j++) {
            const int col = wn + j * 16 + cl;
#pragma unroll
            for (int r = 0; r < 4; r++) {
                const int row = wm + i * 16 + q * 4 + r;
                SM[row * 136 + col] = f2bf(acc[i][j][r]);
            }
        }
    __syncthreads();

    if (z < 2) {
        ushort_t* ob = (z == 0) ? qb : kb;
        if (z == 1) {
#pragma unroll
            for (int t = 0; t < 4; t++) {
                const int g = t * 256 + tid, f = g >> 3, kbg = (g & 7) ^ (f & 7);
                gload16(projb + (size_t)f * 64 + kbg * 8, PS + (size_t)g * 8);
            }
        }
#pragma unroll
        for (int p = 0; p < 16; p++) {
            const int idx = p * 256 + tid;
            const int row = idx >> 5, c4 = idx & 31;
            ushort4 o = *(const ushort4*)&SM[row * 136 + c4 * 4];
            *(ushort4*)(ob + (size_t)(m0 + row) * DIMM + n0 + c4 * 4) = o;
        }
        if (z == 1) {
            const int bb = m0 >> 11;
            const int h0 = n0 >> 6;
            float mx[2] = {-3.0e38f, -3.0e38f};
#pragma unroll
            for (int half = 0; half < 2; half++) {
                __syncthreads();   // PS DMA drained; prior-half frag reads done
#pragma unroll
                for (int hh = 0; hh < 2; hh++) {
                    floatx4 a2[4][4];
#pragma unroll
                    for (int i = 0; i < 4; i++)
#pragma unroll
                        for (int j = 0; j < 4; j++) a2[i][j] = zero;
#pragma unroll
                    for (int ks = 0; ks < 2; ks++) {
                        bf16x8 af[4], bfr[4];
#pragma unroll
                        for (int i = 0; i < 4; i++)
                            af[i] = *(const bf16x8*)&SM[(wm + i * 16 + cl) * 136 + hh * 64 + (ks * 4 + q) * 8];
#pragma unroll
                        for (int j = 0; j < 4; j++)
                            bfr[j] = frag8(PS, wn + j * 16 + cl, ks * 4 + q);
#pragma unroll
                        for (int i = 0; i < 4; i++)
#pragma unroll
                            for (int j = 0; j < 4; j++)
                                a2[i][j] = __builtin_amdgcn_mfma_f32_16x16x32_bf16(
                                    af[i], bfr[j], a2[i][j], 0, 0, 0);
                    }
#pragma unroll
                    for (int i = 0; i < 4; i++)
#pragma unroll
                        for (int j = 0; j < 4; j++)
#pragma unroll
                            for (int r = 0; r < 4; r++) mx[hh] = fmaxf(mx[hh], a2[i][j][r]);
                }
                if (half == 0) {
                    __syncthreads();
#pragma unroll
                    for (int t = 0; t < 4; t++) {
                        const int g = t * 256 + tid, f = g >> 3, kbg = (g & 7) ^ (f & 7);
                        gload16(projb + (size_t)(128 + f) * 64 + kbg * 8, PS + (size_t)g * 8);
                    }
                }
            }
#pragma unroll
            for (int hh = 0; hh < 2; hh++) {
                __syncthreads();
                red[tid] = mx[hh];
                __syncthreads();
                for (int s = 128; s > 0; s >>= 1) {
                    if (tid < s) red[tid] = fmaxf(red[tid], red[tid + s]);
                    __syncthreads();
                }
                if (tid == 0) atomicMax(&mk_u[bb * NH + h0 + hh], enc_f(red[0]));
            }
        }
    } else {
        const int bb = m0 >> 11, nbase = m0 & 2047;
#pragma unroll
        for (int p = 0; p < 16; p++) {
            const int idx = p * 256 + tid;
            const int cl2 = idx >> 5, n4 = idx & 31;
            const int C = n0 + cl2;
            const int h = C >> 6, e = C & 63;
            union { ushort4 v4; unsigned short s[4]; } pk;
#pragma unroll
            for (int k = 0; k < 4; k++) pk.s[k] = SM[(n4 * 4 + k) * 136 + cl2];
            *(ushort4*)(vTb + (((size_t)(bb * NH + h) * 64 + e)) * NSEQ + nbase + n4 * 4) = pk.v4;
        }
    }
}

// ---------- output projection: 64x128 tiles, grid 256, double-buffered ----------
__device__ __forceinline__ void mm24(const ushort_t* A, const ushort_t* B,
                                     floatx4 acc[2][4], int wm, int wn, int c, int q)
{
#pragma unroll
    for (int ks = 0; ks < 2; ks++) {
        bf16x8 af[2], bfr[4];
#pragma unroll
        for (int i = 0; i < 2; i++) af[i] = frag8(A, wm + i * 16 + c, ks * 4 + q);
#pragma unroll
        for (int j = 0; j < 4; j++) bfr[j] = frag8(B, wn + j * 16 + c, ks * 4 + q);
#pragma unroll
        for (int i = 0; i < 2; i++)
#pragma unroll
            for (int j = 0; j < 4; j++)
                acc[i][j] = __builtin_amdgcn_mfma_f32_16x16x32_bf16(
                    af[i], bfr[j], acc[i][j], 0, 0, 0);
    }
}

__global__ __launch_bounds__(256)
void gemm_out(const ushort_t* __restrict__ attnb, const ushort_t* __restrict__ Wto,
              float* __restrict__ out, const float* __restrict__ bias)
{
    __shared__ alignas(16) ushort_t A0[4096];
    __shared__ alignas(16) ushort_t A1[4096];
    __shared__ alignas(16) ushort_t B0[8192];
    __shared__ alignas(16) ushort_t B1[8192];
    const int tid = threadIdx.x;
    const int n0 = blockIdx.x * 128, m0 = blockIdx.y * 64;
    const ushort_t* AG = attnb + (size_t)m0 * DIMM;
    const ushort_t* BG = Wto + (size_t)n0 * DIMM;

    floatx4 zero = {0.f, 0.f, 0.f, 0.f};
    floatx4 acc[2][4];
#pragma unroll
    for (int i = 0; i < 2; i++)
#pragma unroll
        for (int j = 0; j < 4; j++) acc[i][j] = zero;

    const int lane = tid & 63, wid = tid >> 6;
    const int q = lane >> 4, c = lane & 15;
    const int wm = (wid >> 1) * 32, wn = (wid & 1) * 64;

    stage4h(AG, A0, DIMM, tid);
    stage8(BG, B0, DIMM, tid);
    __syncthreads();
    for (int tt = 0; tt < 4; tt++) {
        const int k0 = tt * 128;
        stage4h(AG + k0 + 64, A1, DIMM, tid);
        stage8(BG + k0 + 64, B1, DIMM, tid);
        mm24(A0, B0, acc, wm, wn, c, q);
        __syncthreads();                         // A1/B1 resident; A0/B0 reads done
        if (tt < 3) {
            stage4h(AG + k0 + 128, A0, DIMM, tid);
            stage8(BG + k0 + 128, B0, DIMM, tid);
        }
        mm24(A1, B1, acc, wm, wn, c, q);
        __syncthreads();                         // A0/B0 resident; A1/B1 reads done
    }

#pragma unroll
    for (int i = 0; i < 2; i++)
#pragma unroll
        for (int j = 0; j < 4; j++) {
            const int col = n0 + wn + j * 16 + c;
            const float bv = bias[col];
#pragma unroll
            for (int r = 0; r < 4; r++) {
                const int row = m0 + wm + i * 16 + q * 4 + r;
                out[(size_t)row * DIMM + col] = acc[i][j][r] + bv;
            }
        }
}

// =====================================================================
// featk, f-half blocks: grid (32, 8, 2) = 512 blocks, 2 blocks/CU.
// Each block: kf chunk [128 rows][128 f-half] + Ksum half + CTXT half.
// =====================================================================
__global__ __launch_bounds__(256)
void featk(const ushort_t* __restrict__ kb_, const ushort_t* __restrict__ projb,
           const unsigned* __restrict__ mk_u, const ushort_t* __restrict__ vTb,
           ushort_t* __restrict__ kfb, float* __restrict__ CTXT,
           float* __restrict__ Ksum)
{
    __shared__ alignas(16) ushort_t SM[17408];  // As(8192)+Bs(8192) -> kf-tile[128][136] -> T[64][136]
    __shared__ alignas(16) ushort_t Vs[8192];   // V tile 64 x 128 (fragS), dedicated
    __shared__ float dtmp[256];
    __shared__ float diag_l[128];
    __shared__ float colp[2][128];
    ushort_t* As = SM;
    ushort_t* Bs = SM + 8192;
    const int tid = threadIdx.x, lane = tid & 63, wid = tid >> 6;
    const int q = lane >> 4, cl = lane & 15;
    const int m0 = blockIdx.x * 128, h = blockIdx.y, fh = blockIdx.z;
    const int bb = m0 >> 11, nloc = m0 & 2047;
    const int bh = bb * NH + h;
    const int cidx = nloc >> 7;
    const ushort_t* Aq = kb_ + (size_t)m0 * DIMM + h * 64;
    const ushort_t* Vg = vTb + ((size_t)bh * 64) * NSEQ + nloc;
    const ushort_t* Pj = projb + (size_t)fh * 128 * 64;

    // diag[row] = sum(k^2)/16
    {
        const int row = tid >> 1, half = tid & 1;
        float s = 0.f;
        const ushort_t* p = Aq + (size_t)row * DIMM + half * 32;
#pragma unroll
        for (int d = 0; d < 32; d += 4) {
            ushort4 w = *(const ushort4*)(p + d);
            float a = bf2f(w.x), b2 = bf2f(w.y), c2 = bf2f(w.z), d2 = bf2f(w.w);
            s += a * a + b2 * b2 + c2 * c2 + d2 * d2;
        }
        dtmp[tid] = s;
    }
    stage8(Aq, As, DIMM, tid);      // kb chunk 128 x 64
    stage8(Pj, Bs, 64, tid);        // proj f-half 128 x 64
    stageV(Vg, Vs, tid);            // V tile 64 x 128
    __syncthreads();                                    // S0
    if (tid < 128) diag_l[tid] = (dtmp[2 * tid] + dtmp[2 * tid + 1]) * 0.0625f;

    floatx4 zero = {0.f, 0.f, 0.f, 0.f};
    floatx4 acc[4][4];
#pragma unroll
    for (int i = 0; i < 4; i++)
#pragma unroll
        for (int j = 0; j < 4; j++) acc[i][j] = zero;
    const int wm = (wid >> 1) * 64, wn = (wid & 1) * 64;
#pragma unroll
    for (int ks = 0; ks < 2; ks++) {
        bf16x8 af[4], bfr[4];
#pragma unroll
        for (int i = 0; i < 4; i++) af[i] = frag8(As, wm + i * 16 + cl, ks * 4 + q);
#pragma unroll
        for (int j = 0; j < 4; j++) bfr[j] = frag8(Bs, wn + j * 16 + cl, ks * 4 + q);
#pragma unroll
        for (int i = 0; i < 4; i++)
#pragma unroll
            for (int j = 0; j < 4; j++)
                acc[i][j] = __builtin_amdgcn_mfma_f32_16x16x32_bf16(
                    af[i], bfr[j], acc[i][j], 0, 0, 0);
    }
    __syncthreads();                                    // S1: frag reads done; diag_l visible

    const float mk = dec_f(mk_u[bh]);
#pragma unroll
    for (int i = 0; i < 4; i++)
#pragma unroll
        for (int r = 0; r < 4; r++) {
            const int row = wm + i * 16 + q * 4 + r;
            const float cc = diag_l[row] + mk;
#pragma unroll
            for (int j = 0; j < 4; j++)
                acc[i][j][r] = 0.0625f * (__expf(acc[i][j][r] - cc) + 1.0e-4f);
        }

    // column sums (over 128 rows): colp[row-group][col]
#pragma unroll
    for (int j = 0; j < 4; j++) {
        float s = 0.f;
#pragma unroll
        for (int i = 0; i < 4; i++)
            s += acc[i][j][0] + acc[i][j][1] + acc[i][j][2] + acc[i][j][3];
        s += __shfl_xor(s, 16);
        s += __shfl_xor(s, 32);
        if (q == 0) colp[wid >> 1][wn + j * 16 + cl] = s;
    }

    // kf tile -> SM (stride 136, 16B-aligned rows)
#pragma unroll
    for (int i = 0; i < 4; i++)
#pragma unroll
        for (int j = 0; j < 4; j++) {
            const int col = wn + j * 16 + cl;
#pragma unroll
            for (int r = 0; r < 4; r++) {
                const int row = wm + i * 16 + q * 4 + r;
                SM[row * 136 + col] = f2bf(acc[i][j][r]);
            }
        }
    __syncthreads();                                    // S2: tile + colp visible

    if (tid < 128)
        Ksum[((size_t)bh * NCHK + cidx) * FF + fh * 128 + tid] = colp[0][tid] + colp[1][tid];

    const size_t frow = (size_t)bh * NSEQ + nloc;
#pragma unroll
    for (int p = 0; p < 16; p++) {
        const int idx = p * 256 + tid;
        const int row = idx >> 5, c4 = idx & 31;
        ushort4 o = *(const ushort4*)&SM[row * 136 + c4 * 4];
        *(ushort4*)(kfb + (frow + row) * FF + fh * 128 + c4 * 4) = o;
    }
    __syncthreads();                                    // S3: SM reads done (T reuse)

    // fused ctx: CTXT[bh][cidx][e][fh*128 + f] = sum_n vT[e][n] * kf[n][f]
    ushort_t* T = SM;
    const size_t cbase = ((size_t)bh * NCHK + cidx) * 64;
#pragma unroll
    for (int fq = 0; fq < 2; fq++) {
        if ((wid & 1) == fq) {
#pragma unroll
            for (int jj = 0; jj < 4; jj++) {
#pragma unroll
                for (int i = 0; i < 4; i++)
#pragma unroll
                    for (int r = 0; r < 4; r++) {
                        const int n = wm + i * 16 + q * 4 + r;
                        T[(jj * 16 + cl) * 136 + n] = f2bf(acc[i][jj][r]);
                    }
            }
        }
        __syncthreads();                                // T ready
        floatx4 accc[4];
#pragma unroll
        for (int jj = 0; jj < 4; jj++) accc[jj] = zero;
#pragma unroll
        for (int kt = 0; kt < 4; kt++) {
            const bf16x8 av = fragS(Vs, wid * 16 + cl, kt * 4 + q);
#pragma unroll
            for (int jj = 0; jj < 4; jj++) {
                const bf16x8 bv = *(const bf16x8*)(T + (jj * 16 + cl) * 136 + (kt * 4 + q) * 8);
                accc[jj] = __builtin_amdgcn_mfma_f32_16x16x32_bf16(av, bv, accc[jj], 0, 0, 0);
            }
        }
#pragma unroll
        for (int jj = 0; jj < 4; jj++) {
            const int f = fh * 128 + fq * 64 + jj * 16 + cl;
#pragma unroll
            for (int r = 0; r < 4; r++) {
                const int e = wid * 16 + q * 4 + r;
                CTXT[(cbase + e) * FF + f] = accc[jj][r];
            }
        }
        __syncthreads();
    }
}

// ---------- merged exclusive prefixes: blocks [0,1024) S-path, [1024,1040) Z-path ----------
__global__ void prefix_zs(float* __restrict__ Ksum, float* __restrict__ Zout,
                          const float* __restrict__ CTXT, ushort_t* __restrict__ ctxp,
                          float* __restrict__ Sout)
{
    const int b = blockIdx.x;
    if (b < 1024) {
        const int idx = b * 256 + threadIdx.x;
        const int bh = idx >> 14, ef = idx & 16383;
        const int e = ef >> 8, f = ef & 255;
        float run = 0.f;
#pragma unroll
        for (int c = 0; c < NCHK; c++) {
            const size_t o = (((size_t)bh * NCHK + c) * 64 + e) * FF + f;
            const float t = CTXT[o];
            ctxp[o] = f2bf(run);
            run += t;
        }
        Sout[((size_t)bh * FF + f) * 64 + e] = run;   // S[b,h,f,e]
    } else {
        const int idx = (b - 1024) * 256 + threadIdx.x;
        const int bh = idx >> 8, f = idx & 255;
        float run = 0.f;
#pragma unroll
        for (int c = 0; c < NCHK; c++) {
            const size_t o = ((size_t)(bh * NCHK + c)) * FF + f;
            const float t = Ksum[o];
            Ksum[o] = run;
            run += t;
        }
        Zout[(size_t)bh * FF + f] = run;
    }
}

// ---- stage-1 k-step: acc1[j] += qf_slice x Kf_tile (A rows = wave's 16 q-rows)
template<int NJ>
__device__ __forceinline__ void st1N(const ushort_t* QFs, const ushort_t* Bk,
                                     floatx4* acc1, int wv, int cl, int q)
{
#pragma unroll
    for (int ks = 0; ks < 2; ks++) {
        const bf16x8 af = frag8(QFs, wv * 16 + cl, ks * 4 + q);
        bf16x8 bfr[NJ];
#pragma unroll
        for (int j = 0; j < NJ; j++) bfr[j] = frag8(Bk, j * 16 + cl, ks * 4 + q);
#pragma unroll
        for (int j = 0; j < NJ; j++)
            acc1[j] = __builtin_amdgcn_mfma_f32_16x16x32_bf16(af, bfr[j], acc1[j], 0, 0, 0);
    }
}

// ---- stage-4 k-tile: acc2[i] += Cp_tile x qf_slice
__device__ __forceinline__ void pv4(const ushort_t* CpB, const ushort_t* QFs,
                                    floatx4 acc2[4], int wv, int cl, int q)
{
#pragma unroll
    for (int ks = 0; ks < 2; ks++) {
        const bf16x8 bfr = frag8(QFs, wv * 16 + cl, ks * 4 + q);
#pragma unroll
        for (int i = 0; i < 4; i++) {
            const bf16x8 af = frag8(CpB, i * 16 + cl, ks * 4 + q);
            acc2[i] = __builtin_amdgcn_mfma_f32_16x16x32_bf16(af, bfr, acc2[i], 0, 0, 0);
        }
    }
}

// =====================================================================
// chunk output, half-chunk blocks: 512 blocks (bh x chunk x half),
// 64 q-rows each, 2 blocks/CU. hq=0 blocks skip the fully-masked upper
// 64 KV columns: half Kf staging, half st1 MFMAs, half V/stage-3 work.
// =====================================================================
__global__ __launch_bounds__(256)
void chunk_out_half(const ushort_t* __restrict__ qb_, const ushort_t* __restrict__ projb,
                    const ushort_t* __restrict__ kfb, const ushort_t* __restrict__ vTb,
                    const float* __restrict__ Zex, const ushort_t* __restrict__ ctxp,
                    ushort_t* __restrict__ attnb)
{
    __shared__ alignas(16) ushort_t QF[16384];   // 32KB: qf [64 rows][256 f], 4 frag8 slices
    __shared__ alignas(16) ushort_t BufA[8192];  // 16KB: proj h0 / Kf odd / Vt / Cp1-2
    __shared__ alignas(16) ushort_t Ssl[8192];   // 16KB: proj h1 / Kf even / S / out-tile
    __shared__ alignas(16) ushort_t BufB[4096];  // 8KB:  q tile / Cp0 / Cp3
    __shared__ float zeps[256];
    __shared__ float dtmp[256];
    __shared__ float diag_l[64];
    __shared__ float rows_part[64];
    __shared__ float denp[256];
    __shared__ float den_l[64];

    const int tid = threadIdx.x, lane = tid & 63, wv = tid >> 6;
    const int q = lane >> 4, cl = lane & 15;
    const int bh = blockIdx.x >> 5, r5 = blockIdx.x & 31;
    const int c = r5 >> 1, hq = r5 & 1;
    const int bb = bh >> 3, h = bh & 7;
    const int n0 = c * CHK, q0 = n0 + hq * 64;
    const ushort_t* Kf = kfb + ((size_t)bh * NSEQ + n0) * FF;
    const ushort_t* Aq = qb_ + ((size_t)(bb * NSEQ + q0)) * DIMM + h * 64;
    const ushort_t* Vt = vTb + ((size_t)bh * 64) * NSEQ + n0;
    const ushort_t* Cp = ctxp + ((size_t)bh * NCHK + c) * 64 * FF;

    zeps[tid] = Zex[((size_t)bh * NCHK + c) * FF + tid] + 1.0e-6f;

    // P0: stage q + both proj halves; diag under the same drain
    stage4h(Aq, BufB, DIMM, tid);
    stage8(projb, BufA, 64, tid);
    stage8(projb + 128 * 64, Ssl, 64, tid);
    {
        const int row = tid >> 2, qd = tid & 3;
        float s = 0.f;
        const ushort_t* p = Aq + (size_t)row * DIMM + qd * 16;
#pragma unroll
        for (int d = 0; d < 16; d += 4) {
            ushort4 w = *(const ushort4*)(p + d);
            float a = bf2f(w.x), b2 = bf2f(w.y), c2 = bf2f(w.z), d2 = bf2f(w.w);
            s += a * a + b2 * b2 + c2 * c2 + d2 * d2;
        }
        dtmp[tid] = s;
    }
    __syncthreads();                                   // S0
    if (tid < 64)
        diag_l[tid] = (dtmp[4 * tid] + dtmp[4 * tid + 1] +
                       dtmp[4 * tid + 2] + dtmp[4 * tid + 3]) * 0.0625f;

    floatx4 zero = {0.f, 0.f, 0.f, 0.f};
    floatx4 accqA[8], accqB[8];
#pragma unroll
    for (int j = 0; j < 8; j++) { accqA[j] = zero; accqB[j] = zero; }
    // qf = q @ proj^T, f-half0 (BufA) and f-half1 (Ssl)
#pragma unroll
    for (int ks = 0; ks < 2; ks++) {
        const bf16x8 af = frag8(BufB, wv * 16 + cl, ks * 4 + q);
#pragma unroll
        for (int j = 0; j < 8; j++) {
            const bf16x8 b0 = frag8(BufA, j * 16 + cl, ks * 4 + q);
            accqA[j] = __builtin_amdgcn_mfma_f32_16x16x32_bf16(af, b0, accqA[j], 0, 0, 0);
        }
#pragma unroll
        for (int j = 0; j < 8; j++) {
            const bf16x8 b1 = frag8(Ssl, j * 16 + cl, ks * 4 + q);
            accqB[j] = __builtin_amdgcn_mfma_f32_16x16x32_bf16(af, b1, accqB[j], 0, 0, 0);
        }
    }
    // per-row max (in-register, shfl over cl lanes)
    float rmax[4];
#pragma unroll
    for (int r = 0; r < 4; r++) {
        float m = -3.0e38f;
#pragma unroll
        for (int j = 0; j < 8; j++) m = fmaxf(m, fmaxf(accqA[j][r], accqB[j][r]));
        m = fmaxf(m, __shfl_xor(m, 1)); m = fmaxf(m, __shfl_xor(m, 2));
        m = fmaxf(m, __shfl_xor(m, 4)); m = fmaxf(m, __shfl_xor(m, 8));
        rmax[r] = m;
    }
    __syncthreads();                                   // S1: all proj/q frag reads done
    // exp + QF write (frag8 layout per 64-f slice)
#pragma unroll
    for (int r = 0; r < 4; r++) {
        const int rowL = wv * 16 + q * 4 + r;
        const float cc = diag_l[rowL] + rmax[r];
#pragma unroll
        for (int j = 0; j < 8; j++) {
            {
                const int col = j * 16 + cl;
                const float v = 0.0625f * (__expf(accqA[j][r] - cc) + 1.0e-4f);
                const int s = col >> 6, fp = col & 63;
                QF[s * 4096 + (rowL * 8 + ((fp >> 3) ^ (rowL & 7))) * 8 + (fp & 7)] = f2bf(v);
            }
            {
                const int col = 128 + j * 16 + cl;
                const float v = 0.0625f * (__expf(accqB[j][r] - cc) + 1.0e-4f);
                const int s = col >> 6, fp = col & 63;
                QF[s * 4096 + (rowL * 8 + ((fp >> 3) ^ (rowL & 7))) * 8 + (fp & 7)] = f2bf(v);
            }
        }
    }
    // issue Kf tile0 -> Ssl (after all QF ds_writes; drained at S2)
    if (hq) stage8(Kf, Ssl, FF, tid); else stage4h(Kf, Ssl, FF, tid);
    __syncthreads();                                   // S2: QF + Kf t0 resident

    // ---- stage 1: S = Q @ Kf^T (K=256); issue next tile, compute current ----
    floatx4 acc1[8];
#pragma unroll
    for (int j = 0; j < 8; j++) acc1[j] = zero;
    if (hq) {
        stage8(Kf + 64, BufA, FF, tid);
        st1N<8>(QF, Ssl, acc1, wv, cl, q);             // t0
        __syncthreads();                               // S3
        stage8(Kf + 128, Ssl, FF, tid);
        st1N<8>(QF + 4096, BufA, acc1, wv, cl, q);     // t1
        __syncthreads();                               // S4
        stage8(Kf + 192, BufA, FF, tid);
        st1N<8>(QF + 8192, Ssl, acc1, wv, cl, q);      // t2
        __syncthreads();                               // S5
        st1N<8>(QF + 12288, BufA, acc1, wv, cl, q);    // t3
    } else {
        stage4h(Kf + 64, BufA, FF, tid);
        st1N<4>(QF, Ssl, acc1, wv, cl, q);             // t0
        __syncthreads();                               // S3
        stage4h(Kf + 128, Ssl, FF, tid);
        st1N<4>(QF + 4096, BufA, acc1, wv, cl, q);     // t1
        __syncthreads();                               // S4
        stage4h(Kf + 192, BufA, FF, tid);
        st1N<4>(QF + 8192, Ssl, acc1, wv, cl, q);      // t2
        __syncthreads();                               // S5
        st1N<4>(QF + 12288, BufA, acc1, wv, cl, q);    // t3
    }

    // causal mask + rowsum + S -> Ssl (fragS layout, 64 rows x 16 granules)
    if (hq) {
#pragma unroll
        for (int r = 0; r < 4; r++) {
            const int rowL = wv * 16 + q * 4 + r;
            const int rowG = 64 + rowL;
            float part = 0.f;
#pragma unroll
            for (int j = 0; j < 8; j++) {
                const int col = j * 16 + cl;
                const float v = (col <= rowG) ? acc1[j][r] : 0.f;
                part += v;
                Ssl[(rowL * 16 + ((col >> 3) ^ (rowL & 15))) * 8 + (col & 7)] = f2bf(v);
            }
            part += __shfl_xor(part, 1); part += __shfl_xor(part, 2);
            part += __shfl_xor(part, 4); part += __shfl_xor(part, 8);
            if (cl == 0) rows_part[rowL] = part;
        }
    } else {
#pragma unroll
        for (int r = 0; r < 4; r++) {
            const int rowL = wv * 16 + q * 4 + r;
            float part = 0.f;
#pragma unroll
            for (int j = 0; j < 4; j++) {
                const int col = j * 16 + cl;
                const float v = (col <= rowL) ? acc1[j][r] : 0.f;
                part += v;
                Ssl[(rowL * 16 + ((col >> 3) ^ (rowL & 15))) * 8 + (col & 7)] = f2bf(v);
            }
            part += __shfl_xor(part, 1); part += __shfl_xor(part, 2);
            part += __shfl_xor(part, 4); part += __shfl_xor(part, 8);
            if (cl == 0) rows_part[rowL] = part;
        }
    }
    __syncthreads();                                   // S6: S visible; t3 reads done

    // issue Vt + Cp0; den partial (register-only) under the same drain
    if (hq) stageV(Vt, BufA, tid); else stage4h(Vt, BufA, NSEQ, tid);  // half-V in frag8 layout
    stage4h(Cp, BufB, FF, tid);
    float dacc = 0.f;
    {
        const int drow = tid >> 2, dq = tid & 3;
        const ushort_t* QQ = QF + dq * 4096;
#pragma unroll
        for (int gi = 0; gi < 8; gi++) {
            const ushort_t* gp = QQ + ((size_t)drow * 8 + (gi ^ (drow & 7))) * 8;
            const int kbase = dq * 64 + gi * 8;
#pragma unroll
            for (int e2 = 0; e2 < 8; e2++)
                dacc = fmaf(bf2f(gp[e2]), zeps[kbase + e2], dacc);
        }
    }
    __syncthreads();                                   // S7: Vt + Cp0 resident

    // ---- stage 3: acc2[e] += vT x S (K = 128 or 64 seq) ----
    floatx4 acc2[4];
#pragma unroll
    for (int i = 0; i < 4; i++) acc2[i] = zero;
    if (hq) {
#pragma unroll
        for (int kk = 0; kk < 4; kk++) {
            const bf16x8 bfr = fragS(Ssl, wv * 16 + cl, kk * 4 + q);
#pragma unroll
            for (int i = 0; i < 4; i++) {
                const bf16x8 af = fragS(BufA, i * 16 + cl, kk * 4 + q);
                acc2[i] = __builtin_amdgcn_mfma_f32_16x16x32_bf16(af, bfr, acc2[i], 0, 0, 0);
            }
        }
    } else {
#pragma unroll
        for (int kk = 0; kk < 2; kk++) {
            const bf16x8 bfr = fragS(Ssl, wv * 16 + cl, kk * 4 + q);
#pragma unroll
            for (int i = 0; i < 4; i++) {
                const bf16x8 af = frag8(BufA, i * 16 + cl, kk * 4 + q);
                acc2[i] = __builtin_amdgcn_mfma_f32_16x16x32_bf16(af, bfr, acc2[i], 0, 0, 0);
            }
        }
    }
    denp[tid] = dacc;
    __syncthreads();                                   // S8: Vt/S reads done

    // ---- stage 4: acc2 += ctxp x qf (K = 256 features) ----
    stage4h(Cp + 64, BufA, FF, tid);
    stage4h(Cp + 128, BufA + 4096, FF, tid);
    pv4(BufB, QF, acc2, wv, cl, q);                    // Cp tile 0
    __syncthreads();                                   // S9: Cp1/2 resident
    stage4h(Cp + 192, BufB, FF, tid);
    pv4(BufA, QF + 4096, acc2, wv, cl, q);             // Cp tile 1
    pv4(BufA + 4096, QF + 8192, acc2, wv, cl, q);      // Cp tile 2
    if (tid < 64)
        den_l[tid] = rows_part[tid] + denp[4 * tid] + denp[4 * tid + 1] +
                     denp[4 * tid + 2] + denp[4 * tid + 3];
    __syncthreads();                                   // S10: Cp3 resident; den_l visible
    pv4(BufB, QF + 12288, acc2, wv, cl, q);            // Cp tile 3

    // ---- epilogue: divide, transpose via LDS, coalesced bf16 store ----
    const float dinv = 1.0f / den_l[wv * 16 + cl];
#pragma unroll
    for (int i = 0; i < 4; i++)
#pragma unroll
        for (int r = 0; r < 4; r++) {
            const int e = i * 16 + q * 4 + r;
            Ssl[(wv * 16 + cl) * 68 + e] = f2bf(acc2[i][r] * dinv);
        }
    __syncthreads();                                   // S11
#pragma unroll
    for (int p = 0; p < 4; p++) {
        const int idx = p * 256 + tid;
        const int row = idx >> 4, e4 = idx & 15;
        ushort4 o = *(const ushort4*)&Ssl[row * 68 + e4 * 4];
        *(ushort4*)(attnb + ((size_t)(bb * NSEQ + q0 + row)) * DIMM + h * 64 + e4 * 4) = o;
    }
}

extern "C" void kernel_launch(void* const* d_in, const int* in_sizes, int n_in,
                              void* d_out, int out_size, void* d_ws, size_t ws_size,
                              hipStream_t stream)
{
    (void)in_sizes; (void)n_in; (void)out_size; (void)ws_size;
    const float* x    = (const float*)d_in[0];
    const float* proj = (const float*)d_in[1];
    const float* Wq   = (const float*)d_in[2];
    const float* Wk   = (const float*)d_in[3];
    const float* Wv   = (const float*)d_in[4];
    const float* Wo   = (const float*)d_in[5];
    const float* bo   = (const float*)d_in[6];
    float* out = (float*)d_out;

    // ---- workspace carve (~61 MB) ----
    char* W = (char*)d_ws;
    float*    CTXT = (float*)W;              W += (size_t)16777216;   // [bh][c][e][f] fp32
    ushort_t* kfb  = (ushort_t*)W;           W += (size_t)16777216;   // [bh][n][f] bf16
    ushort_t* ctxp = (ushort_t*)W;           W += (size_t)8388608;    // [bh][c][e][f] bf16
    ushort_t* qb   = (ushort_t*)W;           W += (size_t)4194304;    // [n][dim] bf16 (live into chunk_out)
    ushort_t* kb   = (ushort_t*)W;           W += (size_t)4194304;
    ushort_t* xb   = (ushort_t*)W;           W += (size_t)4194304;    // reused as attnb
    ushort_t* vTb  = (ushort_t*)W;           W += (size_t)4194304;    // [bh][e][n]
    ushort_t* Wtq  = (ushort_t*)W;           W += (size_t)524288;
    ushort_t* Wtk  = (ushort_t*)W;           W += (size_t)524288;
    ushort_t* Wtv  = (ushort_t*)W;           W += (size_t)524288;
    ushort_t* Wto  = (ushort_t*)W;           W += (size_t)524288;
    ushort_t* projb = (ushort_t*)W;          W += (size_t)32768;
    float*    Ksum = (float*)W;              W += (size_t)262144;     // [bh][c][f]
    unsigned* mk_u = (unsigned*)W;           W += (size_t)256;

    ushort_t* attnb = xb;          // xb dead after gemm_qkv

    float* Zout = out + (size_t)4096 * 512;
    float* Sout = Zout + (size_t)NBH * FF;

    hipLaunchKernelGGL(prep, dim3(3089), dim3(256), 0, stream,
                       x, proj, Wq, Wk, Wv, Wo, xb, projb, Wtq, Wtk, Wtv, Wto, mk_u);
    hipLaunchKernelGGL(gemm_qkv, dim3(384), dim3(256), 0, stream,
                       xb, Wtq, Wtk, Wtv, projb, qb, kb, vTb, mk_u);
    hipLaunchKernelGGL(featk, dim3(32, 8, 2), dim3(256), 0, stream,
                       kb, projb, mk_u, vTb, kfb, CTXT, Ksum);
    hipLaunchKernelGGL(prefix_zs, dim3(1040), dim3(256), 0, stream,
                       Ksum, Zout, CTXT, ctxp, Sout);
    hipLaunchKernelGGL(chunk_out_half, dim3(512), dim3(256), 0, stream,
                       qb, projb, kfb, vTb, Ksum, ctxp, attnb);
    hipLaunchKernelGGL(gemm_out, dim3(4, 64), dim3(256), 0, stream, attnb, Wto, out, bo);
}